// Round 10
// baseline (120.817 us; speedup 1.0000x reference)
//
#include <hip/hip_runtime.h>
#include <cstdint>
#include <climits>

#pragma clang fp contract(off)

#define NCAM 6
#define NCLS 10
#define NKEY 60          // cam*10+cls
#define IMGW 1600
#define IMGH 900
#define CAP 1024         // slab stride per key (dets); avg occupancy ~102
#define CHUNK 256        // dets per scatter block

// XLA-style float->int32: saturate out-of-range, NaN -> 0. (Verified R3/R4.)
__device__ __forceinline__ int sat_f2i(float f) {
    if (f != f) return 0;
    if (f >= 2147483648.0f) return INT_MAX;
    if (f <= -2147483648.0f) return INT_MIN;
    return (int)f;
}

__device__ __forceinline__ int det_key(int m, int M,
                                       const int* __restrict__ det_labels,
                                       const int* __restrict__ det_batch,
                                       const int* __restrict__ det_cam) {
    if (m >= M) return -1;
    int dc = det_cam[m], db = det_batch[m], dl = det_labels[m] - 1;
    if (db != 0 || dc < 0 || dc >= NCAM || dl < 0 || dl >= NCLS) return -1;
    return dc * NCLS + dl;
}

// ---------------- K1: projection + fused hist/scatter ----------------------
// Blocks [0,PB): projection (validated math, unchanged).
// Blocks [PB,PB+NC): chunk c recomputes prior-chunk histogram locally,
// stable-ranks its own chunk, scatters to slab. Chunk 0 zeroes colcnt[].
// Global bucket order = ascending m -> bitwise-identical accumulation.
__global__ __launch_bounds__(256) void prep_kernel(
        const float*  __restrict__ boxes,   // [N][7]
        const float*  __restrict__ ia,      // [6][4][4]
        const float*  __restrict__ la,      // [4][4]
        const float*  __restrict__ l2i,     // [6][4][4]
        const float4* __restrict__ det_boxes,
        const int*    __restrict__ det_labels,
        const float*  __restrict__ det_scores,
        const int*    __restrict__ det_batch,
        const int*    __restrict__ det_cam,
        float* __restrict__ projW,          // [36][N] comp-major
        float* __restrict__ slab,           // [60][CAP][8]
        int*   __restrict__ cnt,            // [60]
        int*   __restrict__ colcnt,         // [PB] done-counters for K2
        int N, int M, int PB, int NC) {
    int tid = threadIdx.x;

    if ((int)blockIdx.x >= PB) {
        // ---- fused hist + stable scatter for chunk c ----
        int c = (int)blockIdx.x - PB;
        __shared__ int base[NKEY];   // counts from chunks < c
        __shared__ int h2[NKEY];     // own-chunk counts (for cnt, last block)
        __shared__ int keys[CHUNK];
        for (int i = tid; i < NKEY; i += 256) { base[i] = 0; h2[i] = 0; }
        if (c == 0 && tid < PB) colcnt[tid] = 0;   // zero K2 done-counters
        __syncthreads();

        int prior = c * CHUNK;
        for (int j = tid; j < prior; j += 256) {
            int kk = det_key(j, M, det_labels, det_batch, det_cam);
            if (kk >= 0) atomicAdd(&base[kk], 1);
        }
        int m = c * CHUNK + tid;
        int key = det_key(m, M, det_labels, det_batch, det_cam);
        keys[tid] = key;
        if (key >= 0) atomicAdd(&h2[key], 1);
        __syncthreads();

        if (key >= 0) {
            int r = 0;
            for (int j = 0; j < tid; j++) r += (keys[j] == key) ? 1 : 0;
            int pos = base[key] + r;
            float4 b = det_boxes[m];
            float area = (b.z - b.x) * (b.w - b.y);
            float4* o = (float4*)(slab + ((size_t)key * CAP + pos) * 8);
            o[0] = b;
            o[1] = make_float4(area, det_scores[m], 0.0f, 0.0f);
        }
        if (c == NC - 1)
            for (int i = tid; i < NKEY; i += 256) cnt[i] = base[i] + h2[i];
        return;
    }

    // ---- projection (validated R3/R4 math — unchanged) ----
    int n = blockIdx.x * 256 + tid;
    if (n >= N) return;
    float bx = boxes[n*7+0], by = boxes[n*7+1], bz = boxes[n*7+2];
    float dx = boxes[n*7+3], dy = boxes[n*7+4], dz = boxes[n*7+5];
    float yaw = boxes[n*7+6];
    float c = (float)cos((double)yaw);
    float s = (float)sin((double)yaw);

    float a00=la[0],a01=la[1],a02=la[2],t0=la[3];
    float a10=la[4],a11=la[5],a12=la[6],t1=la[7];
    float a20=la[8],a21=la[9],a22=la[10],t2=la[11];
    float det = a00*(a11*a22-a12*a21) - a01*(a10*a22-a12*a20) + a02*(a10*a21-a11*a20);
    float id = 1.0f/det;
    float r00=(a11*a22-a12*a21)*id, r01=(a02*a21-a01*a22)*id, r02=(a01*a12-a02*a11)*id;
    float r10=(a12*a20-a10*a22)*id, r11=(a00*a22-a02*a20)*id, r12=(a02*a10-a00*a12)*id;
    float r20=(a10*a21-a11*a20)*id, r21=(a01*a20-a00*a21)*id, r22=(a00*a11-a01*a10)*id;

    float PX[8], PY[8], PZ[8];
    #pragma unroll
    for (int k = 0; k < 8; k++) {
        float sx = ((k==0||k==1||k==4||k==5) ?  0.5f : -0.5f) * dx;
        float sy = ((k==0||k==3||k==4||k==7) ?  0.5f : -0.5f) * dy;
        float sz = ((k>=4)                   ?  0.5f : -0.5f) * dz;
        float cx = sx*c - sy*s + bx;
        float cy = sx*s + sy*c + by;
        float cz = sz + bz;
        float ux = cx - t0, uy = cy - t1, uz = cz - t2;
        PX[k] = r00*ux + r01*uy + r02*uz;
        PY[k] = r10*ux + r11*uy + r12*uz;
        PZ[k] = r20*ux + r21*uy + r22*uz;
    }
    for (int cam = 0; cam < NCAM; cam++) {
        const float* L = l2i + cam*16;
        const float* A = ia  + cam*16;
        int minx = INT_MAX, miny = INT_MAX, maxx = INT_MIN, maxy = INT_MIN;
        #pragma unroll
        for (int k = 0; k < 8; k++) {
            float u = L[0]*PX[k] + L[1]*PY[k] + L[2]*PZ[k]  + L[3];
            float v = L[4]*PX[k] + L[5]*PY[k] + L[6]*PZ[k]  + L[7];
            float w = L[8]*PX[k] + L[9]*PY[k] + L[10]*PZ[k] + L[11];
            float zc = fminf(fmaxf(w, 1e-5f), 100000.0f);
            float x = u / zc, y = v / zc;
            float xx = A[0]*x + A[1]*y + A[2]*zc + A[3];
            float yy = A[4]*x + A[5]*y + A[6]*zc + A[7];
            int pxi = sat_f2i(xx); pxi = min(max(pxi, 0), IMGW);
            int pyi = sat_f2i(yy); pyi = min(max(pyi, 0), IMGH);
            minx = min(minx, pxi); maxx = max(maxx, pxi);
            miny = min(miny, pyi); maxy = max(maxy, pyi);
        }
        float x1 = (float)minx, y1 = (float)miny, x2 = (float)maxx, y2 = (float)maxy;
        float validf = ((x2 - x1) > 0.0f && (y2 - y1) > 0.0f) ? 1.0f : 0.0f;
        projW[(cam*6+0)*N + n] = x1;
        projW[(cam*6+1)*N + n] = y1;
        projW[(cam*6+2)*N + n] = x2;
        projW[(cam*6+3)*N + n] = y2;
        projW[(cam*6+4)*N + n] = (x2 - x1) * (y2 - y1);
        projW[(cam*6+5)*N + n] = validf;
    }
}

// ---------------- K2: main accumulation + last-done-block reduce -----------
// grid (PB, 60). Block (bx,k): 256 boxes vs bucket k.
// R9: K-loop software-pipelined — dets processed in groups of 4 with ONE
// GROUP LOOKAHEAD: next group's 8 uniform loads issue before the current
// group's compute, so the ~200cy L2 latency hides under ~256cy of VALU
// (R8 profile: VALUBusy 40%, dur 41us -> latency-bound). Prefetch may
// overread <=8 float4 past the bucket: always inside the workspace (slab is
// CAP-padded and followed by projW/partial); values are never used.
// Accumulation remains strictly ascending m -> bitwise-identical output.
__global__ __launch_bounds__(256) void main_kernel(
        const float* __restrict__ projW,
        const float* __restrict__ slab,
        const int*   __restrict__ cnt,
        float*       __restrict__ partial,   // [60][N]
        int*         __restrict__ colcnt,    // [PB]
        float*       __restrict__ out,
        int N) {
    int tid = threadIdx.x;
    int k = blockIdx.y;
    int cam = k / NCLS;
    int box = blockIdx.x * 256 + tid;
    __shared__ int last;

    if (box < N) {
        int nk = cnt[k];
        float Px1 = projW[(cam*6+0)*N + box];
        float Py1 = projW[(cam*6+1)*N + box];
        float Px2 = projW[(cam*6+2)*N + box];
        float Py2 = projW[(cam*6+3)*N + box];
        float Pa  = projW[(cam*6+4)*N + box];
        float Pv  = projW[(cam*6+5)*N + box];

        const float4* gk = (const float4*)slab + (size_t)k * CAP * 2;
        float acc = 0.0f;

        int nk4 = nk & ~3;
        // prime the pipeline: group 0 (garbage if nk<4 — never consumed)
        float4 pb0 = gk[0], pq0 = gk[1];
        float4 pb1 = gk[2], pq1 = gk[3];
        float4 pb2 = gk[4], pq2 = gk[5];
        float4 pb3 = gk[6], pq3 = gk[7];

        for (int m = 0; m < nk4; m += 4) {
            float4 cb0 = pb0, cq0 = pq0;
            float4 cb1 = pb1, cq1 = pq1;
            float4 cb2 = pb2, cq2 = pq2;
            float4 cb3 = pb3, cq3 = pq3;
            // issue next group's loads before computing (in-flight overlap)
            int t = 2 * (m + 4);
            pb0 = gk[t+0]; pq0 = gk[t+1];
            pb1 = gk[t+2]; pq1 = gk[t+3];
            pb2 = gk[t+4]; pq2 = gk[t+5];
            pb3 = gk[t+6]; pq3 = gk[t+7];

            #pragma unroll
            for (int j = 0; j < 4; j++) {
                float4 b = (j==0) ? cb0 : (j==1) ? cb1 : (j==2) ? cb2 : cb3;
                float4 q = (j==0) ? cq0 : (j==1) ? cq1 : (j==2) ? cq2 : cq3;
                float ltx = fmaxf(b.x, Px1);
                float lty = fmaxf(b.y, Py1);
                float rbx = fminf(b.z, Px2);
                float rby = fminf(b.w, Py2);
                float iw = fmaxf(rbx - ltx, 0.0f);
                float ih = fmaxf(rby - lty, 0.0f);
                float inter = iw * ih;
                float uni = (q.x + Pa) - inter;
                float r = __fdividef(inter, uni);
                float iou = (uni > 0.0f) ? r : 0.0f;
                acc += iou * q.y;
            }
        }
        // tail (<=3 dets), strictly ascending m
        for (int m = nk4; m < nk; m++) {
            float4 b = gk[2*m];
            float4 q = gk[2*m+1];
            float ltx = fmaxf(b.x, Px1);
            float lty = fmaxf(b.y, Py1);
            float rbx = fminf(b.z, Px2);
            float rby = fminf(b.w, Py2);
            float iw = fmaxf(rbx - ltx, 0.0f);
            float ih = fmaxf(rby - lty, 0.0f);
            float inter = iw * ih;
            float uni = (q.x + Pa) - inter;
            float r = __fdividef(inter, uni);
            float iou = (uni > 0.0f) ? r : 0.0f;
            acc += iou * q.y;
        }
        partial[(size_t)k * N + box] = acc * Pv;
    }

    __syncthreads();                 // drains vmcnt: partial stores in L2
    if (tid == 0) {
        __threadfence();             // release: L2 writeback (cross-XCD)
        last = atomicAdd(&colcnt[blockIdx.x], 1);
    }
    __syncthreads();
    if (last != NKEY - 1) return;

    // ---- last finisher for column bx: reduce + argmax (order unchanged) ----
    __threadfence();                 // acquire: invalidate stale L2 lines
    int n = blockIdx.x * 256 + tid;
    if (n >= N) return;
    float p[NCLS];
    #pragma unroll
    for (int c = 0; c < NCLS; c++) p[c] = 0.0f;
    #pragma unroll
    for (int cc = 0; cc < NCAM; cc++)
        #pragma unroll
        for (int c = 0; c < NCLS; c++)
            p[c] += partial[(size_t)(cc * NCLS + c) * N + n];
    float nv = 0.0f;
    #pragma unroll
    for (int cc = 0; cc < NCAM; cc++) nv += projW[(cc*6+5)*N + n];
    float denom = 1e-5f + nv;
    float best = -1e30f; int bk = 0;
    #pragma unroll
    for (int c = 0; c < NCLS; c++) {
        float v = p[c] / denom;
        if (v > best) { best = v; bk = c; }   // strict >: first-max (jnp.argmax)
    }
    out[n]     = (float)(bk + 1);
    out[N + n] = best;
}

extern "C" void kernel_launch(void* const* d_in, const int* in_sizes, int n_in,
                              void* d_out, int out_size, void* d_ws, size_t ws_size,
                              hipStream_t stream) {
    const float*  pred_boxes = (const float*)d_in[0];
    const float*  ia         = (const float*)d_in[1];
    const float*  la         = (const float*)d_in[2];
    const float*  l2i        = (const float*)d_in[3];
    const float4* det_boxes  = (const float4*)d_in[4];
    const int*    det_labels = (const int*)d_in[5];
    const float*  det_scores = (const float*)d_in[6];
    const int*    det_batch  = (const int*)d_in[7];
    const int*    det_cam    = (const int*)d_in[8];
    float* out = (float*)d_out;

    int N = in_sizes[0] / 7;   // 4096
    int M = in_sizes[4] / 4;   // 6144
    int PB = (N + 255) / 256;  // projection blocks / box columns (16)
    int NC = (M + CHUNK - 1) / CHUNK;  // det chunks (24)

    // ws layout (16B-aligned slabs)
    char* w = (char*)d_ws;
    float* slab    = (float*)w;                               // 60*CAP*8 floats
    size_t off = (size_t)NKEY * CAP * 8 * 4;
    float* projW   = (float*)(w + off);                       // 36*N floats
    off += (size_t)36 * N * 4;
    float* partial = (float*)(w + off);                       // 60*N floats
    off += (size_t)NKEY * N * 4;
    int*   cnt     = (int*)(w + off);                         // 60 ints
    off += (size_t)64 * 4;
    int*   colcnt  = (int*)(w + off);                         // PB ints

    prep_kernel<<<PB + NC, 256, 0, stream>>>(pred_boxes, ia, la, l2i,
                                             det_boxes, det_labels, det_scores,
                                             det_batch, det_cam,
                                             projW, slab, cnt, colcnt,
                                             N, M, PB, NC);
    main_kernel<<<dim3(PB, NKEY), 256, 0, stream>>>(projW, slab, cnt, partial,
                                                    colcnt, out, N);
}

// Round 17
// 111.737 us; speedup vs baseline: 1.0813x; 1.0813x over previous
//
#include <hip/hip_runtime.h>
#include <cstdint>
#include <climits>

#pragma clang fp contract(off)

#define NCAM 6
#define NCLS 10
#define NKEY 60          // cam*10+cls
#define IMGW 1600
#define IMGH 900
#define CAP 1024         // slab stride per key (dets); avg occupancy ~102
#define CHUNK 256        // dets per scatter block

// XLA-style float->int32: saturate out-of-range, NaN -> 0. (Verified R3/R4.)
__device__ __forceinline__ int sat_f2i(float f) {
    if (f != f) return 0;
    if (f >= 2147483648.0f) return INT_MAX;
    if (f <= -2147483648.0f) return INT_MIN;
    return (int)f;
}

__device__ __forceinline__ int det_key(int m, int M,
                                       const int* __restrict__ det_labels,
                                       const int* __restrict__ det_batch,
                                       const int* __restrict__ det_cam) {
    if (m >= M) return -1;
    int dc = det_cam[m], db = det_batch[m], dl = det_labels[m] - 1;
    if (db != 0 || dc < 0 || dc >= NCAM || dl < 0 || dl >= NCLS) return -1;
    return dc * NCLS + dl;
}

// ---------------- K1: projection + fused hist/scatter ----------------------
// Blocks [0,PB): projection (validated math, unchanged).
// Blocks [PB,PB+NC): chunk c recomputes prior-chunk histogram locally,
// stable-ranks its own chunk, scatters to slab.
// Global bucket order = ascending m -> bitwise-identical accumulation.
// (R11: reverted R8's colcnt/fence fusion — measured net -9us regression:
// R4=111.3us vs R8/R9=120.2/120.8us; 960 device-scope fences cost more
// than the one launch they saved.)
__global__ __launch_bounds__(256) void prep_kernel(
        const float*  __restrict__ boxes,   // [N][7]
        const float*  __restrict__ ia,      // [6][4][4]
        const float*  __restrict__ la,      // [4][4]
        const float*  __restrict__ l2i,     // [6][4][4]
        const float4* __restrict__ det_boxes,
        const int*    __restrict__ det_labels,
        const float*  __restrict__ det_scores,
        const int*    __restrict__ det_batch,
        const int*    __restrict__ det_cam,
        float* __restrict__ projW,          // [36][N] comp-major
        float* __restrict__ slab,           // [60][CAP][8]
        int*   __restrict__ cnt,            // [60]
        int N, int M, int PB, int NC) {
    int tid = threadIdx.x;

    if ((int)blockIdx.x >= PB) {
        // ---- fused hist + stable scatter for chunk c ----
        int c = (int)blockIdx.x - PB;
        __shared__ int base[NKEY];   // counts from chunks < c
        __shared__ int h2[NKEY];     // own-chunk counts (for cnt, last block)
        __shared__ int keys[CHUNK];
        for (int i = tid; i < NKEY; i += 256) { base[i] = 0; h2[i] = 0; }
        __syncthreads();

        int prior = c * CHUNK;
        for (int j = tid; j < prior; j += 256) {
            int kk = det_key(j, M, det_labels, det_batch, det_cam);
            if (kk >= 0) atomicAdd(&base[kk], 1);
        }
        int m = c * CHUNK + tid;
        int key = det_key(m, M, det_labels, det_batch, det_cam);
        keys[tid] = key;
        if (key >= 0) atomicAdd(&h2[key], 1);
        __syncthreads();

        if (key >= 0) {
            int r = 0;
            for (int j = 0; j < tid; j++) r += (keys[j] == key) ? 1 : 0;
            int pos = base[key] + r;
            float4 b = det_boxes[m];
            float area = (b.z - b.x) * (b.w - b.y);
            float4* o = (float4*)(slab + ((size_t)key * CAP + pos) * 8);
            o[0] = b;
            o[1] = make_float4(area, det_scores[m], 0.0f, 0.0f);
        }
        if (c == NC - 1)
            for (int i = tid; i < NKEY; i += 256) cnt[i] = base[i] + h2[i];
        return;
    }

    // ---- projection (validated R3/R4 math — unchanged) ----
    int n = blockIdx.x * 256 + tid;
    if (n >= N) return;
    float bx = boxes[n*7+0], by = boxes[n*7+1], bz = boxes[n*7+2];
    float dx = boxes[n*7+3], dy = boxes[n*7+4], dz = boxes[n*7+5];
    float yaw = boxes[n*7+6];
    float c = (float)cos((double)yaw);
    float s = (float)sin((double)yaw);

    float a00=la[0],a01=la[1],a02=la[2],t0=la[3];
    float a10=la[4],a11=la[5],a12=la[6],t1=la[7];
    float a20=la[8],a21=la[9],a22=la[10],t2=la[11];
    float det = a00*(a11*a22-a12*a21) - a01*(a10*a22-a12*a20) + a02*(a10*a21-a11*a20);
    float id = 1.0f/det;
    float r00=(a11*a22-a12*a21)*id, r01=(a02*a21-a01*a22)*id, r02=(a01*a12-a02*a11)*id;
    float r10=(a12*a20-a10*a22)*id, r11=(a00*a22-a02*a20)*id, r12=(a02*a10-a00*a12)*id;
    float r20=(a10*a21-a11*a20)*id, r21=(a01*a20-a00*a21)*id, r22=(a00*a11-a01*a10)*id;

    float PX[8], PY[8], PZ[8];
    #pragma unroll
    for (int k = 0; k < 8; k++) {
        float sx = ((k==0||k==1||k==4||k==5) ?  0.5f : -0.5f) * dx;
        float sy = ((k==0||k==3||k==4||k==7) ?  0.5f : -0.5f) * dy;
        float sz = ((k>=4)                   ?  0.5f : -0.5f) * dz;
        float cx = sx*c - sy*s + bx;
        float cy = sx*s + sy*c + by;
        float cz = sz + bz;
        float ux = cx - t0, uy = cy - t1, uz = cz - t2;
        PX[k] = r00*ux + r01*uy + r02*uz;
        PY[k] = r10*ux + r11*uy + r12*uz;
        PZ[k] = r20*ux + r21*uy + r22*uz;
    }
    for (int cam = 0; cam < NCAM; cam++) {
        const float* L = l2i + cam*16;
        const float* A = ia  + cam*16;
        int minx = INT_MAX, miny = INT_MAX, maxx = INT_MIN, maxy = INT_MIN;
        #pragma unroll
        for (int k = 0; k < 8; k++) {
            float u = L[0]*PX[k] + L[1]*PY[k] + L[2]*PZ[k]  + L[3];
            float v = L[4]*PX[k] + L[5]*PY[k] + L[6]*PZ[k]  + L[7];
            float w = L[8]*PX[k] + L[9]*PY[k] + L[10]*PZ[k] + L[11];
            float zc = fminf(fmaxf(w, 1e-5f), 100000.0f);
            float x = u / zc, y = v / zc;
            float xx = A[0]*x + A[1]*y + A[2]*zc + A[3];
            float yy = A[4]*x + A[5]*y + A[6]*zc + A[7];
            int pxi = sat_f2i(xx); pxi = min(max(pxi, 0), IMGW);
            int pyi = sat_f2i(yy); pyi = min(max(pyi, 0), IMGH);
            minx = min(minx, pxi); maxx = max(maxx, pxi);
            miny = min(miny, pyi); maxy = max(maxy, pyi);
        }
        float x1 = (float)minx, y1 = (float)miny, x2 = (float)maxx, y2 = (float)maxy;
        float validf = ((x2 - x1) > 0.0f && (y2 - y1) > 0.0f) ? 1.0f : 0.0f;
        projW[(cam*6+0)*N + n] = x1;
        projW[(cam*6+1)*N + n] = y1;
        projW[(cam*6+2)*N + n] = x2;
        projW[(cam*6+3)*N + n] = y2;
        projW[(cam*6+4)*N + n] = (x2 - x1) * (y2 - y1);
        projW[(cam*6+5)*N + n] = validf;
    }
}

// ---------------- K2: main accumulation ------------------------------------
// grid (PB, 60). Block (bx,k): 256 boxes vs bucket k. Uniform det reads
// (scalar/broadcast), grouped-4 with one-group lookahead (R9, measured
// neutral). No fences, no fused reduce (R11 revert). Strictly ascending-m
// accumulation -> bitwise-identical output.
__global__ __launch_bounds__(256) void main_kernel(
        const float* __restrict__ projW,
        const float* __restrict__ slab,
        const int*   __restrict__ cnt,
        float*       __restrict__ partial,   // [60][N]
        int N) {
    int tid = threadIdx.x;
    int k = blockIdx.y;
    int cam = k / NCLS;
    int box = blockIdx.x * 256 + tid;
    if (box >= N) return;

    int nk = cnt[k];
    float Px1 = projW[(cam*6+0)*N + box];
    float Py1 = projW[(cam*6+1)*N + box];
    float Px2 = projW[(cam*6+2)*N + box];
    float Py2 = projW[(cam*6+3)*N + box];
    float Pa  = projW[(cam*6+4)*N + box];
    float Pv  = projW[(cam*6+5)*N + box];

    const float4* gk = (const float4*)slab + (size_t)k * CAP * 2;
    float acc = 0.0f;

    int nk4 = nk & ~3;
    // prime the pipeline: group 0 (garbage if nk<4 — never consumed)
    float4 pb0 = gk[0], pq0 = gk[1];
    float4 pb1 = gk[2], pq1 = gk[3];
    float4 pb2 = gk[4], pq2 = gk[5];
    float4 pb3 = gk[6], pq3 = gk[7];

    for (int m = 0; m < nk4; m += 4) {
        float4 cb0 = pb0, cq0 = pq0;
        float4 cb1 = pb1, cq1 = pq1;
        float4 cb2 = pb2, cq2 = pq2;
        float4 cb3 = pb3, cq3 = pq3;
        // issue next group's loads before computing (in-flight overlap)
        int t = 2 * (m + 4);
        pb0 = gk[t+0]; pq0 = gk[t+1];
        pb1 = gk[t+2]; pq1 = gk[t+3];
        pb2 = gk[t+4]; pq2 = gk[t+5];
        pb3 = gk[t+6]; pq3 = gk[t+7];

        #pragma unroll
        for (int j = 0; j < 4; j++) {
            float4 b = (j==0) ? cb0 : (j==1) ? cb1 : (j==2) ? cb2 : cb3;
            float4 q = (j==0) ? cq0 : (j==1) ? cq1 : (j==2) ? cq2 : cq3;
            float ltx = fmaxf(b.x, Px1);
            float lty = fmaxf(b.y, Py1);
            float rbx = fminf(b.z, Px2);
            float rby = fminf(b.w, Py2);
            float iw = fmaxf(rbx - ltx, 0.0f);
            float ih = fmaxf(rby - lty, 0.0f);
            float inter = iw * ih;
            float uni = (q.x + Pa) - inter;
            float r = __fdividef(inter, uni);
            float iou = (uni > 0.0f) ? r : 0.0f;
            acc += iou * q.y;
        }
    }
    // tail (<=3 dets), strictly ascending m
    for (int m = nk4; m < nk; m++) {
        float4 b = gk[2*m];
        float4 q = gk[2*m+1];
        float ltx = fmaxf(b.x, Px1);
        float lty = fmaxf(b.y, Py1);
        float rbx = fminf(b.z, Px2);
        float rby = fminf(b.w, Py2);
        float iw = fmaxf(rbx - ltx, 0.0f);
        float ih = fmaxf(rby - lty, 0.0f);
        float inter = iw * ih;
        float uni = (q.x + Pa) - inter;
        float r = __fdividef(inter, uni);
        float iou = (uni > 0.0f) ? r : 0.0f;
        acc += iou * q.y;
    }
    partial[(size_t)k * N + box] = acc * Pv;
}

// ---------------- K3: reduce over keys + argmax ----------------------------
__global__ __launch_bounds__(256) void reduce_kernel(
        const float* __restrict__ partial,
        const float* __restrict__ projW,
        float* __restrict__ out, int N) {
    int n = blockIdx.x * 256 + threadIdx.x;
    if (n >= N) return;
    float p[NCLS];
    #pragma unroll
    for (int c = 0; c < NCLS; c++) p[c] = 0.0f;
    #pragma unroll
    for (int cam = 0; cam < NCAM; cam++)
        #pragma unroll
        for (int c = 0; c < NCLS; c++)
            p[c] += partial[(size_t)(cam * NCLS + c) * N + n];
    float nv = 0.0f;
    #pragma unroll
    for (int cam = 0; cam < NCAM; cam++) nv += projW[(cam*6+5)*N + n];
    float denom = 1e-5f + nv;
    float best = -1e30f; int bk = 0;
    #pragma unroll
    for (int c = 0; c < NCLS; c++) {
        float v = p[c] / denom;
        if (v > best) { best = v; bk = c; }   // strict >: first-max (jnp.argmax)
    }
    out[n]     = (float)(bk + 1);
    out[N + n] = best;
}

extern "C" void kernel_launch(void* const* d_in, const int* in_sizes, int n_in,
                              void* d_out, int out_size, void* d_ws, size_t ws_size,
                              hipStream_t stream) {
    const float*  pred_boxes = (const float*)d_in[0];
    const float*  ia         = (const float*)d_in[1];
    const float*  la         = (const float*)d_in[2];
    const float*  l2i        = (const float*)d_in[3];
    const float4* det_boxes  = (const float4*)d_in[4];
    const int*    det_labels = (const int*)d_in[5];
    const float*  det_scores = (const float*)d_in[6];
    const int*    det_batch  = (const int*)d_in[7];
    const int*    det_cam    = (const int*)d_in[8];
    float* out = (float*)d_out;

    int N = in_sizes[0] / 7;   // 4096
    int M = in_sizes[4] / 4;   // 6144
    int PB = (N + 255) / 256;  // projection blocks / box columns (16)
    int NC = (M + CHUNK - 1) / CHUNK;  // det chunks (24)

    // ws layout (16B-aligned slabs)
    char* w = (char*)d_ws;
    float* slab    = (float*)w;                               // 60*CAP*8 floats
    size_t off = (size_t)NKEY * CAP * 8 * 4;
    float* projW   = (float*)(w + off);                       // 36*N floats
    off += (size_t)36 * N * 4;
    float* partial = (float*)(w + off);                       // 60*N floats
    off += (size_t)NKEY * N * 4;
    int*   cnt     = (int*)(w + off);                         // 60 ints

    prep_kernel<<<PB + NC, 256, 0, stream>>>(pred_boxes, ia, la, l2i,
                                             det_boxes, det_labels, det_scores,
                                             det_batch, det_cam,
                                             projW, slab, cnt, N, M, PB, NC);
    main_kernel<<<dim3(PB, NKEY), 256, 0, stream>>>(projW, slab, cnt, partial, N);
    reduce_kernel<<<PB, 256, 0, stream>>>(partial, projW, out, N);
}

// Round 18
// 107.581 us; speedup vs baseline: 1.1230x; 1.0386x over previous
//
#include <hip/hip_runtime.h>
#include <cstdint>
#include <climits>

#pragma clang fp contract(off)

#define NCAM 6
#define NCLS 10
#define NKEY 60          // cam*10+cls
#define IMGW 1600
#define IMGH 900
#define CAP 1024         // slab stride per key (dets); avg occupancy ~102
#define CHUNK 256        // dets per scatter block

// XLA-style float->int32: saturate out-of-range, NaN -> 0. (Verified R3/R4.)
__device__ __forceinline__ int sat_f2i(float f) {
    if (f != f) return 0;
    if (f >= 2147483648.0f) return INT_MAX;
    if (f <= -2147483648.0f) return INT_MIN;
    return (int)f;
}

__device__ __forceinline__ int det_key(int m, int M,
                                       const int* __restrict__ det_labels,
                                       const int* __restrict__ det_batch,
                                       const int* __restrict__ det_cam) {
    if (m >= M) return -1;
    int dc = det_cam[m], db = det_batch[m], dl = det_labels[m] - 1;
    if (db != 0 || dc < 0 || dc >= NCAM || dl < 0 || dl >= NCLS) return -1;
    return dc * NCLS + dl;
}

// ---------------- K1: projection + fused hist/scatter ----------------------
// Blocks [0,PB): projection (validated math, unchanged).
// Blocks [PB,PB+NC): chunk c recomputes prior-chunk histogram locally,
// stable-ranks its own chunk, scatters to slab.
// Global bucket order = ascending m -> bitwise-identical accumulation.
__global__ __launch_bounds__(256) void prep_kernel(
        const float*  __restrict__ boxes,   // [N][7]
        const float*  __restrict__ ia,      // [6][4][4]
        const float*  __restrict__ la,      // [4][4]
        const float*  __restrict__ l2i,     // [6][4][4]
        const float4* __restrict__ det_boxes,
        const int*    __restrict__ det_labels,
        const float*  __restrict__ det_scores,
        const int*    __restrict__ det_batch,
        const int*    __restrict__ det_cam,
        float* __restrict__ projW,          // [36][N] comp-major
        float* __restrict__ slab,           // [60][CAP][8]
        int*   __restrict__ cnt,            // [60]
        int N, int M, int PB, int NC) {
    int tid = threadIdx.x;

    if ((int)blockIdx.x >= PB) {
        // ---- fused hist + stable scatter for chunk c ----
        int c = (int)blockIdx.x - PB;
        __shared__ int base[NKEY];   // counts from chunks < c
        __shared__ int h2[NKEY];     // own-chunk counts (for cnt, last block)
        __shared__ int keys[CHUNK];
        for (int i = tid; i < NKEY; i += 256) { base[i] = 0; h2[i] = 0; }
        __syncthreads();

        int prior = c * CHUNK;
        for (int j = tid; j < prior; j += 256) {
            int kk = det_key(j, M, det_labels, det_batch, det_cam);
            if (kk >= 0) atomicAdd(&base[kk], 1);
        }
        int m = c * CHUNK + tid;
        int key = det_key(m, M, det_labels, det_batch, det_cam);
        keys[tid] = key;
        if (key >= 0) atomicAdd(&h2[key], 1);
        __syncthreads();

        if (key >= 0) {
            int r = 0;
            for (int j = 0; j < tid; j++) r += (keys[j] == key) ? 1 : 0;
            int pos = base[key] + r;
            float4 b = det_boxes[m];
            float area = (b.z - b.x) * (b.w - b.y);
            float4* o = (float4*)(slab + ((size_t)key * CAP + pos) * 8);
            o[0] = b;
            o[1] = make_float4(area, det_scores[m], 0.0f, 0.0f);
        }
        if (c == NC - 1)
            for (int i = tid; i < NKEY; i += 256) cnt[i] = base[i] + h2[i];
        return;
    }

    // ---- projection (validated R3/R4 math — unchanged) ----
    int n = blockIdx.x * 256 + tid;
    if (n >= N) return;
    float bx = boxes[n*7+0], by = boxes[n*7+1], bz = boxes[n*7+2];
    float dx = boxes[n*7+3], dy = boxes[n*7+4], dz = boxes[n*7+5];
    float yaw = boxes[n*7+6];
    float c = (float)cos((double)yaw);
    float s = (float)sin((double)yaw);

    float a00=la[0],a01=la[1],a02=la[2],t0=la[3];
    float a10=la[4],a11=la[5],a12=la[6],t1=la[7];
    float a20=la[8],a21=la[9],a22=la[10],t2=la[11];
    float det = a00*(a11*a22-a12*a21) - a01*(a10*a22-a12*a20) + a02*(a10*a21-a11*a20);
    float id = 1.0f/det;
    float r00=(a11*a22-a12*a21)*id, r01=(a02*a21-a01*a22)*id, r02=(a01*a12-a02*a11)*id;
    float r10=(a12*a20-a10*a22)*id, r11=(a00*a22-a02*a20)*id, r12=(a02*a10-a00*a12)*id;
    float r20=(a10*a21-a11*a20)*id, r21=(a01*a20-a00*a21)*id, r22=(a00*a11-a01*a10)*id;

    float PX[8], PY[8], PZ[8];
    #pragma unroll
    for (int k = 0; k < 8; k++) {
        float sx = ((k==0||k==1||k==4||k==5) ?  0.5f : -0.5f) * dx;
        float sy = ((k==0||k==3||k==4||k==7) ?  0.5f : -0.5f) * dy;
        float sz = ((k>=4)                   ?  0.5f : -0.5f) * dz;
        float cx = sx*c - sy*s + bx;
        float cy = sx*s + sy*c + by;
        float cz = sz + bz;
        float ux = cx - t0, uy = cy - t1, uz = cz - t2;
        PX[k] = r00*ux + r01*uy + r02*uz;
        PY[k] = r10*ux + r11*uy + r12*uz;
        PZ[k] = r20*ux + r21*uy + r22*uz;
    }
    for (int cam = 0; cam < NCAM; cam++) {
        const float* L = l2i + cam*16;
        const float* A = ia  + cam*16;
        int minx = INT_MAX, miny = INT_MAX, maxx = INT_MIN, maxy = INT_MIN;
        #pragma unroll
        for (int k = 0; k < 8; k++) {
            float u = L[0]*PX[k] + L[1]*PY[k] + L[2]*PZ[k]  + L[3];
            float v = L[4]*PX[k] + L[5]*PY[k] + L[6]*PZ[k]  + L[7];
            float w = L[8]*PX[k] + L[9]*PY[k] + L[10]*PZ[k] + L[11];
            float zc = fminf(fmaxf(w, 1e-5f), 100000.0f);
            float x = u / zc, y = v / zc;
            float xx = A[0]*x + A[1]*y + A[2]*zc + A[3];
            float yy = A[4]*x + A[5]*y + A[6]*zc + A[7];
            int pxi = sat_f2i(xx); pxi = min(max(pxi, 0), IMGW);
            int pyi = sat_f2i(yy); pyi = min(max(pyi, 0), IMGH);
            minx = min(minx, pxi); maxx = max(maxx, pxi);
            miny = min(miny, pyi); maxy = max(maxy, pyi);
        }
        float x1 = (float)minx, y1 = (float)miny, x2 = (float)maxx, y2 = (float)maxy;
        float validf = ((x2 - x1) > 0.0f && (y2 - y1) > 0.0f) ? 1.0f : 0.0f;
        projW[(cam*6+0)*N + n] = x1;
        projW[(cam*6+1)*N + n] = y1;
        projW[(cam*6+2)*N + n] = x2;
        projW[(cam*6+3)*N + n] = y2;
        projW[(cam*6+4)*N + n] = (x2 - x1) * (y2 - y1);
        projW[(cam*6+5)*N + n] = validf;
    }
}

// ---------------- K2: main accumulation (R18: LDS-staged dets) -------------
// grid (PB, 60). Block (bx,k): 256 boxes vs bucket k.
// R17 confirmed main's uniform det reads compile to in-order s_load (SMEM):
// each group stalls ~200cy; lookahead was measured useless (R10). R18 stages
// the bucket into LDS once (coalesced, ~3.3KB avg, one barrier); inner loop
// reads dets via same-address ds_read_b128 broadcast — conflict-free, deep
// lgkmcnt pipelining, results land in VGPRs (no s->v moves).
// Accumulation remains strictly ascending m -> bitwise-identical output
// (same pattern verified absmax 0.0 in R2).
__global__ __launch_bounds__(256) void main_kernel(
        const float* __restrict__ projW,
        const float* __restrict__ slab,
        const int*   __restrict__ cnt,
        float*       __restrict__ partial,   // [60][N]
        int N) {
    int tid = threadIdx.x;
    int k = blockIdx.y;
    int cam = k / NCLS;
    int box = blockIdx.x * 256 + tid;
    __shared__ float4 sd[CAP * 2];           // 32 KB worst case (nk <= CAP)

    int nk = cnt[k];
    const float4* gk = (const float4*)slab + (size_t)k * CAP * 2;

    // cooperative stage: bucket k -> LDS (coalesced, all threads participate)
    for (int i = tid; i < nk * 2; i += 256)
        sd[i] = gk[i];
    __syncthreads();

    if (box < N) {
        float Px1 = projW[(cam*6+0)*N + box];
        float Py1 = projW[(cam*6+1)*N + box];
        float Px2 = projW[(cam*6+2)*N + box];
        float Py2 = projW[(cam*6+3)*N + box];
        float Pa  = projW[(cam*6+4)*N + box];
        float Pv  = projW[(cam*6+5)*N + box];

        float acc = 0.0f;
        #pragma unroll 4
        for (int m = 0; m < nk; m++) {
            float4 b = sd[2*m];              // broadcast ds_read_b128
            float4 q = sd[2*m+1];
            float ltx = fmaxf(b.x, Px1);
            float lty = fmaxf(b.y, Py1);
            float rbx = fminf(b.z, Px2);
            float rby = fminf(b.w, Py2);
            float iw = fmaxf(rbx - ltx, 0.0f);
            float ih = fmaxf(rby - lty, 0.0f);
            float inter = iw * ih;
            float uni = (q.x + Pa) - inter;
            float r = __fdividef(inter, uni);
            float iou = (uni > 0.0f) ? r : 0.0f;
            acc += iou * q.y;
        }
        partial[(size_t)k * N + box] = acc * Pv;
    }
}

// ---------------- K3: reduce over keys + argmax ----------------------------
__global__ __launch_bounds__(256) void reduce_kernel(
        const float* __restrict__ partial,
        const float* __restrict__ projW,
        float* __restrict__ out, int N) {
    int n = blockIdx.x * 256 + threadIdx.x;
    if (n >= N) return;
    float p[NCLS];
    #pragma unroll
    for (int c = 0; c < NCLS; c++) p[c] = 0.0f;
    #pragma unroll
    for (int cam = 0; cam < NCAM; cam++)
        #pragma unroll
        for (int c = 0; c < NCLS; c++)
            p[c] += partial[(size_t)(cam * NCLS + c) * N + n];
    float nv = 0.0f;
    #pragma unroll
    for (int cam = 0; cam < NCAM; cam++) nv += projW[(cam*6+5)*N + n];
    float denom = 1e-5f + nv;
    float best = -1e30f; int bk = 0;
    #pragma unroll
    for (int c = 0; c < NCLS; c++) {
        float v = p[c] / denom;
        if (v > best) { best = v; bk = c; }   // strict >: first-max (jnp.argmax)
    }
    out[n]     = (float)(bk + 1);
    out[N + n] = best;
}

extern "C" void kernel_launch(void* const* d_in, const int* in_sizes, int n_in,
                              void* d_out, int out_size, void* d_ws, size_t ws_size,
                              hipStream_t stream) {
    const float*  pred_boxes = (const float*)d_in[0];
    const float*  ia         = (const float*)d_in[1];
    const float*  la         = (const float*)d_in[2];
    const float*  l2i        = (const float*)d_in[3];
    const float4* det_boxes  = (const float4*)d_in[4];
    const int*    det_labels = (const int*)d_in[5];
    const float*  det_scores = (const float*)d_in[6];
    const int*    det_batch  = (const int*)d_in[7];
    const int*    det_cam    = (const int*)d_in[8];
    float* out = (float*)d_out;

    int N = in_sizes[0] / 7;   // 4096
    int M = in_sizes[4] / 4;   // 6144
    int PB = (N + 255) / 256;  // projection blocks / box columns (16)
    int NC = (M + CHUNK - 1) / CHUNK;  // det chunks (24)

    // ws layout (16B-aligned slabs)
    char* w = (char*)d_ws;
    float* slab    = (float*)w;                               // 60*CAP*8 floats
    size_t off = (size_t)NKEY * CAP * 8 * 4;
    float* projW   = (float*)(w + off);                       // 36*N floats
    off += (size_t)36 * N * 4;
    float* partial = (float*)(w + off);                       // 60*N floats
    off += (size_t)NKEY * N * 4;
    int*   cnt     = (int*)(w + off);                         // 60 ints

    prep_kernel<<<PB + NC, 256, 0, stream>>>(pred_boxes, ia, la, l2i,
                                             det_boxes, det_labels, det_scores,
                                             det_batch, det_cam,
                                             projW, slab, cnt, N, M, PB, NC);
    main_kernel<<<dim3(PB, NKEY), 256, 0, stream>>>(projW, slab, cnt, partial, N);
    reduce_kernel<<<PB, 256, 0, stream>>>(partial, projW, out, N);
}